// Round 4
// baseline (146.983 us; speedup 1.0000x reference)
//
#include <hip/hip_runtime.h>
#include <hip/hip_bf16.h>

typedef __attribute__((ext_vector_type(8))) short bf16x8;
typedef __attribute__((ext_vector_type(8))) short s16x8;
typedef __attribute__((ext_vector_type(4))) short s16x4;
typedef __attribute__((ext_vector_type(4))) float f32x4;

#define T_LEN 2048
#define S_ENC 256
#define NT 36                           // 4 encoder + 32 self tiles of 64 keys
#define QSCALE 0.18033688011112042f     // 64^-0.5 * log2(e): softmax in log2 domain
#define EXP2(x) exp2f(x)

// raw barrier: drain LDS ops for visibility, but do NOT drain vmcnt --
// prefetch global loads stay in flight across the barrier (T4 principle)
#define BARRIER()                                         \
  do {                                                    \
    asm volatile("s_waitcnt lgkmcnt(0)" ::: "memory");    \
    __builtin_amdgcn_s_barrier();                         \
  } while (0)

__device__ __forceinline__ short f2bf(float x) {
  union { __hip_bfloat16 b; short s; } u;
  u.b = __float2bfloat16(x);
  return u.s;
}

// XOR bank swizzle (T2): 128B rows, 16B slot index ^= row&7.
// col granularity must be >= 8B (bit 2 preserved). Applied on BOTH sides.
__device__ __forceinline__ int swz(int row, int col) {
  return row * 64 + (col ^ ((row & 7) << 3));
}

struct TileSrc { const float* k; const float* v; int stride; int s0; };

__device__ __forceinline__ TileSrc tsrc(int t, const float* kp, const float* vp,
                                        const float* ekp, const float* evp) {
  TileSrc s;
  if (t < 4) { s.k = ekp; s.v = evp; s.stride = S_ENC; s.s0 = 64 * t; }
  else       { s.k = kp;  s.v = vp;  s.stride = T_LEN; s.s0 = 64 * (t - 4); }
  return s;
}

__device__ __forceinline__ void issue_loads(const TileSrc& s, int tid,
                                            float (&kr)[8], f32x4& vr0, f32x4& vr1) {
  const int ks = tid & 63;
  const int kc = (tid >> 6) * 8;
  const float* kp = s.k + (size_t)kc * s.stride + (s.s0 + ks);
#pragma unroll
  for (int r = 0; r < 8; ++r) kr[r] = kp[(size_t)r * s.stride];
  const int vg = tid & 15;
  const int vc = tid >> 4;
  const float* vp0 = s.v + (size_t)vc * s.stride + (s.s0 + 4 * vg);
  vr0 = *(const f32x4*)(vp0);
  vr1 = *(const f32x4*)(vp0 + (size_t)32 * s.stride);
}

__device__ __forceinline__ void stage_write(short* __restrict__ Kt, short* __restrict__ Vt,
                                            int tid, const float (&kr)[8],
                                            const f32x4& vr0, const f32x4& vr1) {
  const int ks = tid & 63;
  const int kc = (tid >> 6) * 8;
  s16x8 kw;
#pragma unroll
  for (int r = 0; r < 8; ++r) kw[r] = f2bf(kr[r]);
  *(s16x8*)(Kt + swz(ks, kc)) = kw;

  const int vg = tid & 15;
  const int vc = tid >> 4;
  const int vcol = 32 * (vg >> 3) + 8 * (vg & 3) + 4 * ((vg >> 2) & 1);  // sigma-perm
  s16x4 vw;
#pragma unroll
  for (int i = 0; i < 4; ++i) vw[i] = f2bf(vr0[i]);
  *(s16x4*)(Vt + swz(vc, vcol)) = vw;
#pragma unroll
  for (int i = 0; i < 4; ++i) vw[i] = f2bf(vr1[i]);
  *(s16x4*)(Vt + swz(vc + 32, vcol)) = vw;
}

__device__ __forceinline__ void compute_tile(const short* __restrict__ Kt,
                                             const short* __restrict__ Vt,
                                             const bf16x8 (&qf)[2][2],
                                             f32x4 (&o)[2][4], float (&lp)[2],
                                             int ln, int lg) {
  // ---- S^T = K * Q : rows = keys, cols = queries ----
  f32x4 sacc[2][4];
#pragma unroll
  for (int qt = 0; qt < 2; ++qt)
#pragma unroll
    for (int mt = 0; mt < 4; ++mt) sacc[qt][mt] = (f32x4){0.f, 0.f, 0.f, 0.f};

#pragma unroll
  for (int mt = 0; mt < 4; ++mt) {
    const int row = 16 * mt + ln;
    const bf16x8 kf0 = *(const bf16x8*)(Kt + swz(row, 8 * lg));
    const bf16x8 kf1 = *(const bf16x8*)(Kt + swz(row, 32 + 8 * lg));
#pragma unroll
    for (int qt = 0; qt < 2; ++qt) {
      sacc[qt][mt] = __builtin_amdgcn_mfma_f32_16x16x32_bf16(kf0, qf[qt][0], sacc[qt][mt], 0, 0, 0);
      sacc[qt][mt] = __builtin_amdgcn_mfma_f32_16x16x32_bf16(kf1, qf[qt][1], sacc[qt][mt], 0, 0, 0);
    }
  }

  // ---- p = 2^s (no max tracking; |s| bounded), tree-reduced row sums ----
  bf16x8 pfrag[2][2];
#pragma unroll
  for (int qt = 0; qt < 2; ++qt) {
    float pmt[4];
#pragma unroll
    for (int mt = 0; mt < 4; ++mt) {
      float p0 = EXP2(sacc[qt][mt][0]);
      float p1 = EXP2(sacc[qt][mt][1]);
      float p2 = EXP2(sacc[qt][mt][2]);
      float p3 = EXP2(sacc[qt][mt][3]);
      pfrag[qt][mt >> 1][4 * (mt & 1) + 0] = f2bf(p0);
      pfrag[qt][mt >> 1][4 * (mt & 1) + 1] = f2bf(p1);
      pfrag[qt][mt >> 1][4 * (mt & 1) + 2] = f2bf(p2);
      pfrag[qt][mt >> 1][4 * (mt & 1) + 3] = f2bf(p3);
      pmt[mt] = (p0 + p1) + (p2 + p3);
    }
    lp[qt] += (pmt[0] + pmt[1]) + (pmt[2] + pmt[3]);
  }

  // ---- O^T += V * P^T ----
#pragma unroll
  for (int sub = 0; sub < 2; ++sub)
#pragma unroll
    for (int ct = 0; ct < 4; ++ct) {
      const bf16x8 vf = *(const bf16x8*)(Vt + swz(16 * ct + ln, 32 * sub + 8 * lg));
#pragma unroll
      for (int qt = 0; qt < 2; ++qt)
        o[qt][ct] = __builtin_amdgcn_mfma_f32_16x16x32_bf16(vf, pfrag[qt][sub], o[qt][ct], 0, 0, 0);
    }
}

__global__ __launch_bounds__(512, 4) void attn_kernel(
    const float* __restrict__ qkv, const float* __restrict__ ekv,
    float* __restrict__ out) {
  const int tid = threadIdx.x;
  const int lane = tid & 63;
  const int wave = tid >> 6;
  const int ln = lane & 15;
  const int lg = lane >> 4;

  // XCD swizzle: all 8 q-blocks of one head land on the same XCD (blk%8 == bh%8)
  const int bh = blockIdx.x & 63;
  const int qb = blockIdx.x >> 6;
  const int t0 = qb * 256 + wave * 32;

  const float* qp  = qkv + (size_t)bh * 192 * T_LEN;
  const float* kp  = qp + (size_t)64 * T_LEN;
  const float* vp  = qp + (size_t)128 * T_LEN;
  const float* ekp = ekv + (size_t)bh * 128 * S_ENC;
  const float* evp = ekp + (size_t)64 * S_ENC;

  __shared__ __attribute__((aligned(16))) short Kt[2][64 * 64];
  __shared__ __attribute__((aligned(16))) short Vt[2][64 * 64];

  // Q fragments (channel mapping 32*kk + 8*lg + j, matching K-frag reads)
  bf16x8 qf[2][2];
#pragma unroll
  for (int qt = 0; qt < 2; ++qt)
#pragma unroll
    for (int kk = 0; kk < 2; ++kk)
#pragma unroll
      for (int j = 0; j < 8; ++j)
        qf[qt][kk][j] =
            f2bf(qp[(size_t)(32 * kk + 8 * lg + j) * T_LEN + (t0 + 16 * qt + ln)] * QSCALE);

  f32x4 o[2][4];
#pragma unroll
  for (int qt = 0; qt < 2; ++qt)
#pragma unroll
    for (int ct = 0; ct < 4; ++ct) o[qt][ct] = (f32x4){0.f, 0.f, 0.f, 0.f};
  float lp[2] = {0.f, 0.f};

  // ---- prologue: stage tile 0, prefetch tile 1 ----
  float kr[8];
  f32x4 vr0, vr1;
  issue_loads(tsrc(0, kp, vp, ekp, evp), tid, kr, vr0, vr1);
  stage_write(&Kt[0][0], &Vt[0][0], tid, kr, vr0, vr1);
  issue_loads(tsrc(1, kp, vp, ekp, evp), tid, kr, vr0, vr1);
  BARRIER();

  // ---- main loop: 1 raw barrier per tile; prefetched loads stay in flight
  // across it (no vmcnt drain), consumed by next iteration's stage_write ----
  int cur = 0;
  for (int t = 0; t < NT; ++t) {
    if (t + 1 < NT) {
      stage_write(&Kt[cur ^ 1][0], &Vt[cur ^ 1][0], tid, kr, vr0, vr1);
      if (t + 2 < NT)
        issue_loads(tsrc(t + 2, kp, vp, ekp, evp), tid, kr, vr0, vr1);
    }
    compute_tile(&Kt[cur][0], &Vt[cur][0], qf, o, lp, ln, lg);
    BARRIER();
    cur ^= 1;
  }

  // ---- epilogue ----
#pragma unroll
  for (int qt = 0; qt < 2; ++qt) {
    float l = lp[qt];
    l += __shfl_xor(l, 16);
    l += __shfl_xor(l, 32);
    const float inv = 1.0f / l;
    float* ob = out + (size_t)bh * 64 * T_LEN + (t0 + 16 * qt + ln);
#pragma unroll
    for (int ct = 0; ct < 4; ++ct)
#pragma unroll
      for (int r = 0; r < 4; ++r)
        ob[(size_t)(16 * ct + 4 * lg + r) * T_LEN] = o[qt][ct][r] * inv;
  }
}

extern "C" void kernel_launch(void* const* d_in, const int* in_sizes, int n_in,
                              void* d_out, int out_size, void* d_ws, size_t ws_size,
                              hipStream_t stream) {
  const float* qkv = (const float*)d_in[0];
  const float* ekv = (const float*)d_in[1];
  float* out = (float*)d_out;
  attn_kernel<<<dim3(512), dim3(512), 0, stream>>>(qkv, ekv, out);
}

// Round 5
// 123.414 us; speedup vs baseline: 1.1910x; 1.1910x over previous
//
#include <hip/hip_runtime.h>
#include <hip/hip_bf16.h>

typedef __attribute__((ext_vector_type(8))) short bf16x8;
typedef __attribute__((ext_vector_type(8))) short s16x8;
typedef __attribute__((ext_vector_type(4))) short s16x4;
typedef __attribute__((ext_vector_type(4))) float f32x4;

#define T_LEN 2048
#define S_ENC 256
#define QSCALE 0.18033688011112042f     // 64^-0.5 * log2(e): softmax in log2 domain
#define EXP2(x) exp2f(x)

// raw barrier: drain LDS ops for visibility, but do NOT drain vmcnt --
// in-flight global loads (register destinations) ride across it.
#define BARRIER()                                         \
  do {                                                    \
    asm volatile("s_waitcnt lgkmcnt(0)" ::: "memory");    \
    __builtin_amdgcn_s_barrier();                         \
  } while (0)

__device__ __forceinline__ short f2bf(float x) {
  union { __hip_bfloat16 b; short s; } u;
  u.b = __float2bfloat16(x);
  return u.s;
}

// XOR bank swizzle (T2, verified: conflicts 9.4M -> 0): rows of 64 shorts
// (128B), 16B-slot index ^= row&7. Applied on BOTH write and read sides.
__device__ __forceinline__ int swz(int row, int col) {
  return row * 64 + (col ^ ((row & 7) << 3));
}

// One 64-key tile (R2 structure: loads -> barrier -> write -> barrier -> compute)
template<int STRIDE>
__device__ __forceinline__ void tile_body(
    const float* __restrict__ kb, const float* __restrict__ vb, int s0,
    short* __restrict__ Kt, short* __restrict__ Vt,
    const bf16x8 (&qf)[2][2], f32x4 (&o)[2][4], float (&lp)[2], int tid) {

  const int lane = tid & 63;
  const int ln = lane & 15;
  const int lg = lane >> 4;

  // ---- issue staging loads (compile-time stride) ----
  const int ks = tid & 63;
  const int kc = (tid >> 6) * 8;
  float kr[8];
  const float* kp = kb + (size_t)kc * STRIDE + (s0 + ks);
#pragma unroll
  for (int r = 0; r < 8; ++r) kr[r] = kp[(size_t)r * STRIDE];

  const int vg = tid & 15;
  const int vc = tid >> 4;
  const float* vp0 = vb + (size_t)vc * STRIDE + (s0 + 4 * vg);
  f32x4 vr0 = *(const f32x4*)(vp0);
  f32x4 vr1 = *(const f32x4*)(vp0 + (size_t)32 * STRIDE);

  BARRIER();   // prior tile's LDS reads complete (lgkm only; loads stay in flight)

  // ---- stage to LDS (bank-conflict-free via swz) ----
  s16x8 kw;
#pragma unroll
  for (int r = 0; r < 8; ++r) kw[r] = f2bf(kr[r]);
  *(s16x8*)(Kt + swz(ks, kc)) = kw;

  const int vcol = 32 * (vg >> 3) + 8 * (vg & 3) + 4 * ((vg >> 2) & 1);  // sigma-perm
  s16x4 vw;
#pragma unroll
  for (int i = 0; i < 4; ++i) vw[i] = f2bf(vr0[i]);
  *(s16x4*)(Vt + swz(vc, vcol)) = vw;
#pragma unroll
  for (int i = 0; i < 4; ++i) vw[i] = f2bf(vr1[i]);
  *(s16x4*)(Vt + swz(vc + 32, vcol)) = vw;

  BARRIER();   // tile staged

  // ---- S^T = K * Q : rows = keys, cols = queries ----
  f32x4 sacc[2][4];
#pragma unroll
  for (int qt = 0; qt < 2; ++qt)
#pragma unroll
    for (int mt = 0; mt < 4; ++mt) sacc[qt][mt] = (f32x4){0.f, 0.f, 0.f, 0.f};

#pragma unroll
  for (int mt = 0; mt < 4; ++mt) {
    const int row = 16 * mt + ln;
    const bf16x8 kf0 = *(const bf16x8*)(Kt + swz(row, 8 * lg));
    const bf16x8 kf1 = *(const bf16x8*)(Kt + swz(row, 32 + 8 * lg));
#pragma unroll
    for (int qt = 0; qt < 2; ++qt) {
      sacc[qt][mt] = __builtin_amdgcn_mfma_f32_16x16x32_bf16(kf0, qf[qt][0], sacc[qt][mt], 0, 0, 0);
      sacc[qt][mt] = __builtin_amdgcn_mfma_f32_16x16x32_bf16(kf1, qf[qt][1], sacc[qt][mt], 0, 0, 0);
    }
  }

  // ---- p = 2^s (no max tracking; |s| bounded), tree-reduced row sums ----
  bf16x8 pfrag[2][2];
#pragma unroll
  for (int qt = 0; qt < 2; ++qt) {
    float pmt[4];
#pragma unroll
    for (int mt = 0; mt < 4; ++mt) {
      float p0 = EXP2(sacc[qt][mt][0]);
      float p1 = EXP2(sacc[qt][mt][1]);
      float p2 = EXP2(sacc[qt][mt][2]);
      float p3 = EXP2(sacc[qt][mt][3]);
      pfrag[qt][mt >> 1][4 * (mt & 1) + 0] = f2bf(p0);
      pfrag[qt][mt >> 1][4 * (mt & 1) + 1] = f2bf(p1);
      pfrag[qt][mt >> 1][4 * (mt & 1) + 2] = f2bf(p2);
      pfrag[qt][mt >> 1][4 * (mt & 1) + 3] = f2bf(p3);
      pmt[mt] = (p0 + p1) + (p2 + p3);
    }
    lp[qt] += (pmt[0] + pmt[1]) + (pmt[2] + pmt[3]);
  }

  // ---- O^T += V * P^T ----
#pragma unroll
  for (int sub = 0; sub < 2; ++sub)
#pragma unroll
    for (int ct = 0; ct < 4; ++ct) {
      const bf16x8 vf = *(const bf16x8*)(Vt + swz(16 * ct + ln, 32 * sub + 8 * lg));
#pragma unroll
      for (int qt = 0; qt < 2; ++qt)
        o[qt][ct] = __builtin_amdgcn_mfma_f32_16x16x32_bf16(vf, pfrag[qt][sub], o[qt][ct], 0, 0, 0);
    }
}

__global__ __launch_bounds__(512, 4) void attn_kernel(
    const float* __restrict__ qkv, const float* __restrict__ ekv,
    float* __restrict__ out) {
  const int tid = threadIdx.x;
  const int lane = tid & 63;
  const int wave = tid >> 6;
  const int ln = lane & 15;
  const int lg = lane >> 4;

  // XCD swizzle (verified: FETCH 315->74 MB): all 8 q-blocks of one head
  // land on the same XCD (blk%8 == bh%8 for all of them)
  const int bh = blockIdx.x & 63;
  const int qb = blockIdx.x >> 6;
  const int t0 = qb * 256 + wave * 32;

  const float* qp  = qkv + (size_t)bh * 192 * T_LEN;
  const float* kp  = qp + (size_t)64 * T_LEN;
  const float* vp  = qp + (size_t)128 * T_LEN;
  const float* ekp = ekv + (size_t)bh * 128 * S_ENC;
  const float* evp = ekp + (size_t)64 * S_ENC;

  __shared__ __attribute__((aligned(16))) short Kt[64 * 64];
  __shared__ __attribute__((aligned(16))) short Vt[64 * 64];

  // Q fragments (channel mapping 32*kk + 8*lg + j, matching K-frag reads)
  bf16x8 qf[2][2];
#pragma unroll
  for (int qt = 0; qt < 2; ++qt)
#pragma unroll
    for (int kk = 0; kk < 2; ++kk)
#pragma unroll
      for (int j = 0; j < 8; ++j)
        qf[qt][kk][j] =
            f2bf(qp[(size_t)(32 * kk + 8 * lg + j) * T_LEN + (t0 + 16 * qt + ln)] * QSCALE);

  f32x4 o[2][4];
#pragma unroll
  for (int qt = 0; qt < 2; ++qt)
#pragma unroll
    for (int ct = 0; ct < 4; ++ct) o[qt][ct] = (f32x4){0.f, 0.f, 0.f, 0.f};
  float lp[2] = {0.f, 0.f};

  for (int st = 0; st < 4; ++st)
    tile_body<S_ENC>(ekp, evp, 64 * st, Kt, Vt, qf, o, lp, tid);
  for (int st = 0; st < 32; ++st)
    tile_body<T_LEN>(kp, vp, 64 * st, Kt, Vt, qf, o, lp, tid);

  // ---- epilogue: reduce l across the 4 lane-groups, normalize, store O^T ----
#pragma unroll
  for (int qt = 0; qt < 2; ++qt) {
    float l = lp[qt];
    l += __shfl_xor(l, 16);
    l += __shfl_xor(l, 32);
    const float inv = 1.0f / l;
    float* ob = out + (size_t)bh * 64 * T_LEN + (t0 + 16 * qt + ln);
#pragma unroll
    for (int ct = 0; ct < 4; ++ct)
#pragma unroll
      for (int r = 0; r < 4; ++r)
        ob[(size_t)(16 * ct + 4 * lg + r) * T_LEN] = o[qt][ct][r] * inv;
  }
}

extern "C" void kernel_launch(void* const* d_in, const int* in_sizes, int n_in,
                              void* d_out, int out_size, void* d_ws, size_t ws_size,
                              hipStream_t stream) {
  const float* qkv = (const float*)d_in[0];
  const float* ekv = (const float*)d_in[1];
  float* out = (float*)d_out;
  attn_kernel<<<dim3(512), dim3(512), 0, stream>>>(qkv, ekv, out);
}

// Round 6
// 98.974 us; speedup vs baseline: 1.4851x; 1.2469x over previous
//
#include <hip/hip_runtime.h>
#include <hip/hip_bf16.h>

typedef __attribute__((ext_vector_type(8))) short bf16x8;
typedef __attribute__((ext_vector_type(4))) float f32x4;
typedef __attribute__((ext_vector_type(4))) unsigned u32x4;
typedef __attribute__((ext_vector_type(2))) unsigned u32x2;

#define T_LEN 2048
#define S_ENC 256
#define QSCALE 0.18033688011112042f     // 64^-0.5 * log2(e): softmax in log2 domain

// raw barrier: drain LDS ops for visibility, but do NOT drain vmcnt --
// in-flight global loads (register destinations) ride across it.
#define BARRIER()                                         \
  do {                                                    \
    asm volatile("s_waitcnt lgkmcnt(0)" ::: "memory");    \
    __builtin_amdgcn_s_barrier();                         \
  } while (0)

__device__ __forceinline__ float exp2_hw(float x) {
#if __has_builtin(__builtin_amdgcn_exp2f)
  return __builtin_amdgcn_exp2f(x);
#else
  float r;
  asm("v_exp_f32 %0, %1" : "=v"(r) : "v"(x));
  return r;
#endif
}

// hardware packed f32->bf16 (RNE), 2 values per instruction
__device__ __forceinline__ unsigned cvt_pk_bf16(float lo, float hi) {
  unsigned r;
  asm("v_cvt_pk_bf16_f32 %0, %1, %2" : "=v"(r) : "v"(lo), "v"(hi));
  return r;
}

__device__ __forceinline__ short f2bf(float x) {   // cold path (Q frag) only
  union { __hip_bfloat16 b; short s; } u;
  u.b = __float2bfloat16(x);
  return u.s;
}

// XOR bank swizzle (T2, verified: conflicts 9.4M -> 0): rows of 64 shorts
// (128B), 16B-slot index ^= row&7. Applied on BOTH write and read sides.
__device__ __forceinline__ int swz(int row, int col) {
  return row * 64 + (col ^ ((row & 7) << 3));
}

union PU { u32x4 u; bf16x8 b; };

// One 64-key tile (R2 structure: loads -> barrier -> write -> barrier -> compute)
template<int STRIDE>
__device__ __forceinline__ void tile_body(
    const float* __restrict__ kb, const float* __restrict__ vb, int s0,
    short* __restrict__ Kt, short* __restrict__ Vt,
    const bf16x8 (&qf)[2][2], f32x4 (&o)[2][4], float (&lp)[2], int tid) {

  const int lane = tid & 63;
  const int ln = lane & 15;
  const int lg = lane >> 4;

  // ---- issue staging loads (compile-time stride) ----
  const int ks = tid & 63;
  const int kc = (tid >> 6) * 8;
  float kr[8];
  const float* kp = kb + (size_t)kc * STRIDE + (s0 + ks);
#pragma unroll
  for (int r = 0; r < 8; ++r) kr[r] = kp[(size_t)r * STRIDE];

  const int vg = tid & 15;
  const int vc = tid >> 4;
  const float* vp0 = vb + (size_t)vc * STRIDE + (s0 + 4 * vg);
  f32x4 vr0 = *(const f32x4*)(vp0);
  f32x4 vr1 = *(const f32x4*)(vp0 + (size_t)32 * STRIDE);

  BARRIER();   // prior tile's LDS reads complete (lgkm only; loads stay in flight)

  // ---- stage to LDS (bank-conflict-free via swz; hw packed cvt) ----
  u32x4 kw;
#pragma unroll
  for (int r = 0; r < 4; ++r) kw[r] = cvt_pk_bf16(kr[2 * r], kr[2 * r + 1]);
  *(u32x4*)(Kt + swz(ks, kc)) = kw;

  const int vcol = 32 * (vg >> 3) + 8 * (vg & 3) + 4 * ((vg >> 2) & 1);  // sigma-perm
  u32x2 vw0, vw1;
  vw0[0] = cvt_pk_bf16(vr0[0], vr0[1]);
  vw0[1] = cvt_pk_bf16(vr0[2], vr0[3]);
  *(u32x2*)(Vt + swz(vc, vcol)) = vw0;
  vw1[0] = cvt_pk_bf16(vr1[0], vr1[1]);
  vw1[1] = cvt_pk_bf16(vr1[2], vr1[3]);
  *(u32x2*)(Vt + swz(vc + 32, vcol)) = vw1;

  BARRIER();   // tile staged

  // ---- S^T = K * Q : rows = keys, cols = queries ----
  f32x4 sacc[2][4];
#pragma unroll
  for (int qt = 0; qt < 2; ++qt)
#pragma unroll
    for (int mt = 0; mt < 4; ++mt) sacc[qt][mt] = (f32x4){0.f, 0.f, 0.f, 0.f};

#pragma unroll
  for (int mt = 0; mt < 4; ++mt) {
    const int row = 16 * mt + ln;
    const bf16x8 kf0 = *(const bf16x8*)(Kt + swz(row, 8 * lg));
    const bf16x8 kf1 = *(const bf16x8*)(Kt + swz(row, 32 + 8 * lg));
#pragma unroll
    for (int qt = 0; qt < 2; ++qt) {
      sacc[qt][mt] = __builtin_amdgcn_mfma_f32_16x16x32_bf16(kf0, qf[qt][0], sacc[qt][mt], 0, 0, 0);
      sacc[qt][mt] = __builtin_amdgcn_mfma_f32_16x16x32_bf16(kf1, qf[qt][1], sacc[qt][mt], 0, 0, 0);
    }
  }

  // ---- p = 2^s (hw exp2; no max tracking, |s| bounded), packed bf16 P ----
  PU pfrag[2][2];
#pragma unroll
  for (int qt = 0; qt < 2; ++qt) {
    float pmt[4];
#pragma unroll
    for (int mt = 0; mt < 4; ++mt) {
      float p0 = exp2_hw(sacc[qt][mt][0]);
      float p1 = exp2_hw(sacc[qt][mt][1]);
      float p2 = exp2_hw(sacc[qt][mt][2]);
      float p3 = exp2_hw(sacc[qt][mt][3]);
      pfrag[qt][mt >> 1].u[2 * (mt & 1) + 0] = cvt_pk_bf16(p0, p1);
      pfrag[qt][mt >> 1].u[2 * (mt & 1) + 1] = cvt_pk_bf16(p2, p3);
      pmt[mt] = (p0 + p1) + (p2 + p3);
    }
    lp[qt] += (pmt[0] + pmt[1]) + (pmt[2] + pmt[3]);
  }

  // ---- O^T += V * P^T ----
#pragma unroll
  for (int sub = 0; sub < 2; ++sub)
#pragma unroll
    for (int ct = 0; ct < 4; ++ct) {
      const bf16x8 vf = *(const bf16x8*)(Vt + swz(16 * ct + ln, 32 * sub + 8 * lg));
#pragma unroll
      for (int qt = 0; qt < 2; ++qt)
        o[qt][ct] = __builtin_amdgcn_mfma_f32_16x16x32_bf16(vf, pfrag[qt][sub].b, o[qt][ct], 0, 0, 0);
    }
}

__global__ __launch_bounds__(512, 4) void attn_kernel(
    const float* __restrict__ qkv, const float* __restrict__ ekv,
    float* __restrict__ out) {
  const int tid = threadIdx.x;
  const int lane = tid & 63;
  const int wave = tid >> 6;
  const int ln = lane & 15;
  const int lg = lane >> 4;

  // XCD swizzle (verified: FETCH 315->74 MB): all 8 q-blocks of one head
  // land on the same XCD (blk%8 == bh%8 for all of them)
  const int bh = blockIdx.x & 63;
  const int qb = blockIdx.x >> 6;
  const int t0 = qb * 256 + wave * 32;

  const float* qp  = qkv + (size_t)bh * 192 * T_LEN;
  const float* kp  = qp + (size_t)64 * T_LEN;
  const float* vp  = qp + (size_t)128 * T_LEN;
  const float* ekp = ekv + (size_t)bh * 128 * S_ENC;
  const float* evp = ekp + (size_t)64 * S_ENC;

  __shared__ __attribute__((aligned(16))) short Kt[64 * 64];
  __shared__ __attribute__((aligned(16))) short Vt[64 * 64];

  // Q fragments (channel mapping 32*kk + 8*lg + j, matching K-frag reads)
  bf16x8 qf[2][2];
#pragma unroll
  for (int qt = 0; qt < 2; ++qt)
#pragma unroll
    for (int kk = 0; kk < 2; ++kk)
#pragma unroll
      for (int j = 0; j < 8; ++j)
        qf[qt][kk][j] =
            f2bf(qp[(size_t)(32 * kk + 8 * lg + j) * T_LEN + (t0 + 16 * qt + ln)] * QSCALE);

  f32x4 o[2][4];
#pragma unroll
  for (int qt = 0; qt < 2; ++qt)
#pragma unroll
    for (int ct = 0; ct < 4; ++ct) o[qt][ct] = (f32x4){0.f, 0.f, 0.f, 0.f};
  float lp[2] = {0.f, 0.f};

  for (int st = 0; st < 4; ++st)
    tile_body<S_ENC>(ekp, evp, 64 * st, Kt, Vt, qf, o, lp, tid);
  for (int st = 0; st < 32; ++st)
    tile_body<T_LEN>(kp, vp, 64 * st, Kt, Vt, qf, o, lp, tid);

  // ---- epilogue: reduce l across the 4 lane-groups, normalize, store O^T ----
#pragma unroll
  for (int qt = 0; qt < 2; ++qt) {
    float l = lp[qt];
    l += __shfl_xor(l, 16);
    l += __shfl_xor(l, 32);
    const float inv = 1.0f / l;
    float* ob = out + (size_t)bh * 64 * T_LEN + (t0 + 16 * qt + ln);
#pragma unroll
    for (int ct = 0; ct < 4; ++ct)
#pragma unroll
      for (int r = 0; r < 4; ++r)
        ob[(size_t)(16 * ct + 4 * lg + r) * T_LEN] = o[qt][ct][r] * inv;
  }
}

extern "C" void kernel_launch(void* const* d_in, const int* in_sizes, int n_in,
                              void* d_out, int out_size, void* d_ws, size_t ws_size,
                              hipStream_t stream) {
  const float* qkv = (const float*)d_in[0];
  const float* ekv = (const float*)d_in[1];
  float* out = (float*)d_out;
  attn_kernel<<<dim3(512), dim3(512), 0, stream>>>(qkv, ekv, out);
}

// Round 8
// 88.152 us; speedup vs baseline: 1.6674x; 1.1228x over previous
//
#include <hip/hip_runtime.h>
#include <hip/hip_bf16.h>

typedef __attribute__((ext_vector_type(8))) short bf16x8;
typedef __attribute__((ext_vector_type(4))) float f32x4;
typedef __attribute__((ext_vector_type(4))) unsigned u32x4;
typedef __attribute__((ext_vector_type(2))) unsigned u32x2;

#define T_LEN 2048
#define S_ENC 256
#define QSCALE 0.18033688011112042f     // 64^-0.5 * log2(e): softmax in log2 domain

// raw barrier: drain LDS ops for visibility, but do NOT drain vmcnt --
// in-flight global loads (register destinations) ride across it.
#define BARRIER()                                         \
  do {                                                    \
    asm volatile("s_waitcnt lgkmcnt(0)" ::: "memory");    \
    __builtin_amdgcn_s_barrier();                         \
  } while (0)

__device__ __forceinline__ float exp2_hw(float x) {
#if __has_builtin(__builtin_amdgcn_exp2f)
  return __builtin_amdgcn_exp2f(x);
#else
  float r;
  asm("v_exp_f32 %0, %1" : "=v"(r) : "v"(x));
  return r;
#endif
}

// hardware packed f32->bf16 (RNE), 2 values per instruction
__device__ __forceinline__ unsigned cvt_pk_bf16(float lo, float hi) {
  unsigned r;
  asm("v_cvt_pk_bf16_f32 %0, %1, %2" : "=v"(r) : "v"(lo), "v"(hi));
  return r;
}

__device__ __forceinline__ short f2bf(float x) {   // cold path (Q frag) only
  union { __hip_bfloat16 b; short s; } u;
  u.b = __float2bfloat16(x);
  return u.s;
}

// XOR bank swizzle (T2, verified: conflicts 9.4M -> 0): rows of 64 shorts
// (128B), 16B-slot index ^= row&7. Applied on BOTH write and read sides.
__device__ __forceinline__ int swz(int row, int col) {
  return row * 64 + (col ^ ((row & 7) << 3));
}

union PU { u32x4 u; bf16x8 b; };

// One 64-key tile. 512-thread block stages (VERBATIM R6 pattern); each of the
// 8 waves computes 64 queries (qt=4). K fragments hoisted once (kf[4][2]);
// QK^T + softmax in two qt-pairs to bound sacc live range (<256 regs total).
template<int STRIDE>
__device__ __forceinline__ void tile_body(
    const float* __restrict__ kb, const float* __restrict__ vb, int s0,
    short* __restrict__ Kt, short* __restrict__ Vt,
    const bf16x8 (&qf)[4][2], f32x4 (&o)[4][4], float (&lp)[4], int tid) {

  const int lane = tid & 63;
  const int ln = lane & 15;
  const int lg = lane >> 4;

  // ---- issue staging loads (compile-time stride; R6 verbatim) ----
  const int ks = tid & 63;
  const int kc = (tid >> 6) * 8;
  float kr[8];
  const float* kp = kb + (size_t)kc * STRIDE + (s0 + ks);
#pragma unroll
  for (int r = 0; r < 8; ++r) kr[r] = kp[(size_t)r * STRIDE];

  const int vg = tid & 15;
  const int vc = tid >> 4;
  const float* vp0 = vb + (size_t)vc * STRIDE + (s0 + 4 * vg);
  f32x4 vr0 = *(const f32x4*)(vp0);
  f32x4 vr1 = *(const f32x4*)(vp0 + (size_t)32 * STRIDE);

  BARRIER();   // prior tile's LDS reads complete (lgkm only; loads stay in flight)

  // ---- stage to LDS (bank-conflict-free via swz; hw packed cvt) ----
  u32x4 kw;
#pragma unroll
  for (int r = 0; r < 4; ++r) kw[r] = cvt_pk_bf16(kr[2 * r], kr[2 * r + 1]);
  *(u32x4*)(Kt + swz(ks, kc)) = kw;

  const int vcol = 32 * (vg >> 3) + 8 * (vg & 3) + 4 * ((vg >> 2) & 1);  // sigma-perm
  u32x2 vw0, vw1;
  vw0[0] = cvt_pk_bf16(vr0[0], vr0[1]);
  vw0[1] = cvt_pk_bf16(vr0[2], vr0[3]);
  *(u32x2*)(Vt + swz(vc, vcol)) = vw0;
  vw1[0] = cvt_pk_bf16(vr1[0], vr1[1]);
  vw1[1] = cvt_pk_bf16(vr1[2], vr1[3]);
  *(u32x2*)(Vt + swz(vc + 32, vcol)) = vw1;

  BARRIER();   // tile staged

  // ---- hoist all K fragments once: 8 x ds_read_b128 serve all 4 q-subtiles ----
  bf16x8 kf[4][2];
#pragma unroll
  for (int mt = 0; mt < 4; ++mt) {
    const int row = 16 * mt + ln;
    kf[mt][0] = *(const bf16x8*)(Kt + swz(row, 8 * lg));
    kf[mt][1] = *(const bf16x8*)(Kt + swz(row, 32 + 8 * lg));
  }

  // ---- S^T = K * Q and softmax, in two qt-pairs (bounds sacc live range) ----
  PU pfrag[4][2];
#pragma unroll
  for (int pr = 0; pr < 2; ++pr) {
    f32x4 sacc[2][4];
#pragma unroll
    for (int q2 = 0; q2 < 2; ++q2)
#pragma unroll
      for (int mt = 0; mt < 4; ++mt) sacc[q2][mt] = (f32x4){0.f, 0.f, 0.f, 0.f};

#pragma unroll
    for (int mt = 0; mt < 4; ++mt)
#pragma unroll
      for (int q2 = 0; q2 < 2; ++q2) {
        const int qt = 2 * pr + q2;
        sacc[q2][mt] = __builtin_amdgcn_mfma_f32_16x16x32_bf16(kf[mt][0], qf[qt][0], sacc[q2][mt], 0, 0, 0);
        sacc[q2][mt] = __builtin_amdgcn_mfma_f32_16x16x32_bf16(kf[mt][1], qf[qt][1], sacc[q2][mt], 0, 0, 0);
      }

    // p = 2^s (hw exp2; no max tracking, |s| bounded), packed bf16 P
#pragma unroll
    for (int q2 = 0; q2 < 2; ++q2) {
      const int qt = 2 * pr + q2;
      float pmt[4];
#pragma unroll
      for (int mt = 0; mt < 4; ++mt) {
        float p0 = exp2_hw(sacc[q2][mt][0]);
        float p1 = exp2_hw(sacc[q2][mt][1]);
        float p2 = exp2_hw(sacc[q2][mt][2]);
        float p3 = exp2_hw(sacc[q2][mt][3]);
        pfrag[qt][mt >> 1].u[2 * (mt & 1) + 0] = cvt_pk_bf16(p0, p1);
        pfrag[qt][mt >> 1].u[2 * (mt & 1) + 1] = cvt_pk_bf16(p2, p3);
        pmt[mt] = (p0 + p1) + (p2 + p3);
      }
      lp[qt] += (pmt[0] + pmt[1]) + (pmt[2] + pmt[3]);
    }
  }

  // ---- O^T += V * P^T (each vf read feeds 4 MFMAs) ----
#pragma unroll
  for (int sub = 0; sub < 2; ++sub)
#pragma unroll
    for (int ct = 0; ct < 4; ++ct) {
      const bf16x8 vf = *(const bf16x8*)(Vt + swz(16 * ct + ln, 32 * sub + 8 * lg));
#pragma unroll
      for (int qt = 0; qt < 4; ++qt)
        o[qt][ct] = __builtin_amdgcn_mfma_f32_16x16x32_bf16(vf, pfrag[qt][sub].b, o[qt][ct], 0, 0, 0);
    }
}

__global__ __launch_bounds__(512, 2) void attn_kernel(
    const float* __restrict__ qkv, const float* __restrict__ ekv,
    float* __restrict__ out) {
  const int tid = threadIdx.x;
  const int lane = tid & 63;
  const int wave = tid >> 6;
  const int ln = lane & 15;
  const int lg = lane >> 4;

  // XCD swizzle (verified: FETCH 315->74 MB): all 4 q-blocks of one head
  // land on the same XCD (blk%8 == bh%8 for all of them)
  const int bh = blockIdx.x & 63;
  const int qb = blockIdx.x >> 6;        // 0..3
  const int t0 = qb * 512 + wave * 64;   // this wave: queries t0 .. t0+63

  const float* qp  = qkv + (size_t)bh * 192 * T_LEN;
  const float* kp  = qp + (size_t)64 * T_LEN;
  const float* vp  = qp + (size_t)128 * T_LEN;
  const float* ekp = ekv + (size_t)bh * 128 * S_ENC;
  const float* evp = ekp + (size_t)64 * S_ENC;

  __shared__ __attribute__((aligned(16))) short Kt[64 * 64];
  __shared__ __attribute__((aligned(16))) short Vt[64 * 64];

  // Q fragments (channel mapping 32*kk + 8*lg + j, matching K-frag reads)
  bf16x8 qf[4][2];
#pragma unroll
  for (int qt = 0; qt < 4; ++qt)
#pragma unroll
    for (int kk = 0; kk < 2; ++kk)
#pragma unroll
      for (int j = 0; j < 8; ++j)
        qf[qt][kk][j] =
            f2bf(qp[(size_t)(32 * kk + 8 * lg + j) * T_LEN + (t0 + 16 * qt + ln)] * QSCALE);

  f32x4 o[4][4];
#pragma unroll
  for (int qt = 0; qt < 4; ++qt)
#pragma unroll
    for (int ct = 0; ct < 4; ++ct) o[qt][ct] = (f32x4){0.f, 0.f, 0.f, 0.f};
  float lp[4] = {0.f, 0.f, 0.f, 0.f};

  for (int st = 0; st < 4; ++st)
    tile_body<S_ENC>(ekp, evp, 64 * st, Kt, Vt, qf, o, lp, tid);
  for (int st = 0; st < 32; ++st)
    tile_body<T_LEN>(kp, vp, 64 * st, Kt, Vt, qf, o, lp, tid);

  // ---- epilogue: reduce l across the 4 lane-groups, normalize, store O^T ----
#pragma unroll
  for (int qt = 0; qt < 4; ++qt) {
    float l = lp[qt];
    l += __shfl_xor(l, 16);
    l += __shfl_xor(l, 32);
    const float inv = 1.0f / l;
    float* ob = out + (size_t)bh * 64 * T_LEN + (t0 + 16 * qt + ln);
#pragma unroll
    for (int ct = 0; ct < 4; ++ct)
#pragma unroll
      for (int r = 0; r < 4; ++r)
        ob[(size_t)(16 * ct + 4 * lg + r) * T_LEN] = o[qt][ct][r] * inv;
  }
}

extern "C" void kernel_launch(void* const* d_in, const int* in_sizes, int n_in,
                              void* d_out, int out_size, void* d_ws, size_t ws_size,
                              hipStream_t stream) {
  const float* qkv = (const float*)d_in[0];
  const float* ekv = (const float*)d_in[1];
  float* out = (float*)d_out;
  attn_kernel<<<dim3(256), dim3(512), 0, stream>>>(qkv, ekv, out);
}